// Round 3
// baseline (447.706 us; speedup 1.0000x reference)
//
#include <hip/hip_runtime.h>

#define NSAMP   20
#define BROWS   65536
#define RPB     8                     // rows per block
#define BLOCK   320                   // 5 waves; 8 rows x 40 samples = 320 tasks
#define NBLOCKS (BROWS / RPB)         // 8192

// One block = 8 rows of both tensors. Stage rows into LDS de-interleaved
// (knots separate from coeff float2), one thread per (row, sample, pred|true)
// task, partner exchange via __shfl(lane^32). Block partial goes straight to
// a device-scope float accumulator in d_ws; the last block (ticket) writes
// the final mean to d_out. Accumulator+ticket are zeroed by an async memset
// in kernel_launch (d_ws is 0xAA-poisoned before every timed call).
__global__ __launch_bounds__(BLOCK) void bspline_loss_fused(
    const float* __restrict__ pred, const float* __restrict__ tru,
    float* __restrict__ acc_ws, unsigned int* __restrict__ ticket,
    float* __restrict__ out)
{
    __shared__ float  kn[RPB][2][65];   // +1 pad: slice bases differ mod 32 banks
    __shared__ float2 cf[RPB][2][64];
    __shared__ float  wpart[BLOCK / 64];

    const int tid = threadIdx.x;
    const size_t base = (size_t)blockIdx.x * (RPB * 192);

    // ---- stage: de-interleave (knot, cx, cy); rows contiguous in global ----
    #pragma unroll
    for (int tz = 0; tz < 2; ++tz) {
        const float* src = (tz ? tru : pred) + base;
        for (int j = tid; j < RPB * 64; j += BLOCK) {   // 512 triples
            const int row = j >> 6, q = j & 63;
            const float k = src[3 * j];
            const float x = src[3 * j + 1];
            const float y = src[3 * j + 2];
            kn[row][tz][q] = k;
            cf[row][tz][q] = make_float2(x, y);
        }
    }
    __syncthreads();

    // ---- task mapping: partner (pred<->true) sits at lane^32, same wave ----
    const int lane = tid & 63;
    const int wave = tid >> 6;
    const int slot = wave * 32 + (lane & 31);   // 0..159 = row*20 + sample
    const int sel  = lane >> 5;                 // 0 = pred, 1 = true
    const int row  = slot / 20;
    const int s    = slot - row * 20;

    const float*  K = kn[row][sel];
    const float2* C = cf[row][sel];

    // low = kf[3] = 0 always; high = knots[60]
    const float high = K[60];
    const float tv = (float)s * (1.0f / 19.0f) * high;

    // branchless upper_bound over padded 64 knots; reference searches only
    // knots[0..59] -> clamp to 60.
    int pos = 0;
    #pragma unroll
    for (int st = 32; st >= 1; st >>= 1)
        pos += (K[pos + st - 1] <= tv) ? st : 0;
    const int cnt = min(pos, 60);

    // kf[cnt+j] for j=1..6, where kf[m] = (m<4) ? 0 : knots[m-4]
    float kfv[7];
    #pragma unroll
    for (int j = 1; j <= 6; ++j) {
        const int idx = cnt + j - 4;            // in [-3, 62]
        const float v = K[idx < 0 ? 0 : idx];
        kfv[j] = (idx < 0) ? 0.f : v;
    }

    float2 p0 = C[cnt], p1 = C[cnt + 1], p2 = C[cnt + 2], p3 = C[cnt + 3];

    // weights==1 -> w-channel is identically 1; denominators provably > 0
    // (kj index >= 4, knots strictly increasing) -> rcp, no guard.
    auto alphaf = [&](float ki, float kj) {
        return (tv - ki) * __builtin_amdgcn_rcpf(kj - ki);
    };
    auto lerp2 = [](float2 a, float2 b, float al) {
        const float bl = 1.0f - al;
        return make_float2(fmaf(al, b.x, bl * a.x), fmaf(al, b.y, bl * a.y));
    };
    p3 = lerp2(p2, p3, alphaf(kfv[3], kfv[6]));   // l=1,k=3
    p2 = lerp2(p1, p2, alphaf(kfv[2], kfv[5]));   // l=1,k=2
    p1 = lerp2(p0, p1, alphaf(kfv[1], kfv[4]));   // l=1,k=1
    p3 = lerp2(p2, p3, alphaf(kfv[3], kfv[5]));   // l=2,k=3
    p2 = lerp2(p1, p2, alphaf(kfv[2], kfv[4]));   // l=2,k=2
    p3 = lerp2(p2, p3, alphaf(kfv[3], kfv[4]));   // l=3,k=3

    // ---- pair, square, reduce (each pair counted twice -> *0.5) ----
    const float ox = __shfl(p3.x, lane ^ 32, 64);
    const float oy = __shfl(p3.y, lane ^ 32, 64);
    const float dx = p3.x - ox, dy = p3.y - oy;
    float acc = fmaf(dx, dx, dy * dy);
    #pragma unroll
    for (int off = 32; off >= 1; off >>= 1)
        acc += __shfl_down(acc, off, 64);
    if (lane == 0) wpart[wave] = acc;
    __syncthreads();

    if (tid == 0) {
        const float part =
            (wpart[0] + wpart[1] + wpart[2] + wpart[3] + wpart[4]) * 0.5f;
        atomicAdd(acc_ws, part);                  // device-scope
        __threadfence();
        const unsigned int old = atomicAdd(ticket, 1u);
        if (old == NBLOCKS - 1) {
            const float tot = atomicAdd(acc_ws, 0.0f);  // L2 atomic read
            out[0] = tot / (float)((long long)BROWS * NSAMP);
        }
    }
}

extern "C" void kernel_launch(void* const* d_in, const int* in_sizes, int n_in,
                              void* d_out, int out_size, void* d_ws, size_t ws_size,
                              hipStream_t stream) {
    const float* pred = (const float*)d_in[0];
    const float* tru  = (const float*)d_in[1];
    // d_in[2] (true_masks) ignored: reference uses mask = ones.
    float* out = (float*)d_out;
    float* acc_ws = (float*)d_ws;                 // [0]: accumulator
    unsigned int* ticket = (unsigned int*)d_ws + 1;  // [1]: arrival ticket

    hipMemsetAsync(d_ws, 0, 8, stream);           // zero acc + ticket
    bspline_loss_fused<<<NBLOCKS, BLOCK, 0, stream>>>(pred, tru, acc_ws,
                                                      ticket, out);
}

// Round 4
// 133.458 us; speedup vs baseline: 3.3547x; 3.3547x over previous
//
#include <hip/hip_runtime.h>

#define DEG 3
#define NSAMP 20
#define BROWS 65536
#define NKNOT 64
#define ROWS_PER_BLOCK 4
#define NBLOCKS (BROWS / ROWS_PER_BLOCK) /* 16384 */

// One wave (64 lanes) per row. Row data = 64 knot-triples (knot,cx,cy) = 192
// floats = 768 B per tensor, staged to LDS via 48 float4 loads.
// NOTE (R3 post-mortem): do NOT fuse the reduction via same-address global
// atomics — 16384 serialized device-scope RMWs cost ~330 us on gfx950.
__global__ __launch_bounds__(256) void bspline_loss_main(
    const float* __restrict__ pred, const float* __restrict__ tru,
    float* __restrict__ partials)
{
    __shared__ float lds[ROWS_PER_BLOCK][2][192];
    __shared__ float wsum[ROWS_PER_BLOCK];

    const int tid  = threadIdx.x;
    const int wave = tid >> 6;
    const int lane = tid & 63;
    const int row  = blockIdx.x * ROWS_PER_BLOCK + wave;

    if (lane < 48) {
        const float4 p4 = ((const float4*)(pred + (size_t)row * 192))[lane];
        const float4 t4 = ((const float4*)(tru  + (size_t)row * 192))[lane];
        ((float4*)lds[wave][0])[lane] = p4;
        ((float4*)lds[wave][1])[lane] = t4;
    }
    __syncthreads();

    float rx = 0.f, ry = 0.f;
    if (lane < 40) {
        const int sel = (lane >= 20) ? 1 : 0;
        const int s   = sel ? lane - 20 : lane;
        const float* d = lds[wave][sel];   // [64] x (knot, cx, cy)

        // low = 0 always (kf[3] is a leading zero); high = knots[60]
        const float high = d[3 * 60];
        const float t = ((float)s * (1.0f / 19.0f)) * high;

        // cnt = upper_bound over knots[0..59]; searchsorted s_idx = cnt+3,
        // base control-point index = s_idx - DEG = cnt
        int lo = 0, hi = 60;
        while (lo < hi) {
            int mid = (lo + hi) >> 1;
            if (d[3 * mid] <= t) lo = mid + 1; else hi = mid;
        }
        const int cnt = lo;

        float px[4], py[4], pw[4];
        #pragma unroll
        for (int k = 0; k < 4; ++k) {
            px[k] = d[3 * (cnt + k) + 1];
            py[k] = d[3 * (cnt + k) + 2];
            pw[k] = 1.0f;
        }
        // kf[m] = (m < 4) ? 0 : knots[m-4]
        #pragma unroll
        for (int l = 1; l <= DEG; ++l) {
            #pragma unroll
            for (int k = DEG; k >= l; --k) {
                const int i0 = cnt + k;
                const int i1 = cnt + k + (DEG + 1 - l);
                const float ki = (i0 < 4) ? 0.f : d[3 * (i0 - 4)];
                const float kj = (i1 < 4) ? 0.f : d[3 * (i1 - 4)];
                const float denom = kj - ki;
                const float alpha = (denom != 0.f) ? (t - ki) / denom : 0.f;
                const float b0 = 1.0f - alpha;
                px[k] = b0 * px[k - 1] + alpha * px[k];
                py[k] = b0 * py[k - 1] + alpha * py[k];
                pw[k] = b0 * pw[k - 1] + alpha * pw[k];
            }
        }
        rx = px[DEG] / pw[DEG];
        ry = py[DEG] / pw[DEG];
    }

    // pair pred (lanes 0..19) with true (lanes 20..39)
    const float ox = __shfl(rx, lane + 20, 64);
    const float oy = __shfl(ry, lane + 20, 64);
    float acc = 0.f;
    if (lane < 20) {
        const float dx = rx - ox, dy = ry - oy;
        acc = dx * dx + dy * dy;
    }
    #pragma unroll
    for (int off = 32; off >= 1; off >>= 1)
        acc += __shfl_down(acc, off, 64);
    if (lane == 0) wsum[wave] = acc;
    __syncthreads();
    if (tid == 0)
        partials[blockIdx.x] = wsum[0] + wsum[1] + wsum[2] + wsum[3];
}

__global__ __launch_bounds__(256) void bspline_loss_reduce(
    const float* __restrict__ partials, float* __restrict__ out)
{
    const int tid = threadIdx.x;
    double acc = 0.0;
    const float4* p4 = (const float4*)partials;
    #pragma unroll 4
    for (int i = tid; i < NBLOCKS / 4; i += 256) {
        const float4 v = p4[i];
        acc += (double)v.x + (double)v.y + (double)v.z + (double)v.w;
    }
    #pragma unroll
    for (int off = 32; off >= 1; off >>= 1)
        acc += __shfl_down(acc, off, 64);
    __shared__ double ws[4];
    if ((tid & 63) == 0) ws[tid >> 6] = acc;
    __syncthreads();
    if (tid == 0) {
        const double tot = ws[0] + ws[1] + ws[2] + ws[3];
        out[0] = (float)(tot / (double)((long long)BROWS * NSAMP));
    }
}

extern "C" void kernel_launch(void* const* d_in, const int* in_sizes, int n_in,
                              void* d_out, int out_size, void* d_ws, size_t ws_size,
                              hipStream_t stream) {
    const float* pred = (const float*)d_in[0];
    const float* tru  = (const float*)d_in[1];
    // d_in[2] (true_masks) ignored: reference uses mask = ones.
    float* out      = (float*)d_out;
    float* partials = (float*)d_ws;   // 16384 floats = 64 KB

    bspline_loss_main<<<NBLOCKS, 256, 0, stream>>>(pred, tru, partials);
    bspline_loss_reduce<<<1, 256, 0, stream>>>(partials, out);
}